// Round 3
// baseline (332.918 us; speedup 1.0000x reference)
//
#include <hip/hip_runtime.h>

// GCN 2-layer + pool + head, R18: LDS-staged partition pass fixes k_binsc write thrash.
// R17's k_binsc (160us, 50% of runtime) had 10x write amplification (WRITE 160MB for 16MB
// payload): per-(block,bucket) chunks filled by LDS-cursor atomics spread over the block's
// whole lifetime -> partial 64B lines evicted + refetched ~10x (FETCH 24.6MB read-back).
// Fix (k_part): per block, (A) histogram whole tile -> reserve one contiguous chunk per
// bucket; (B) per 8192-edge sub-tile: LDS histogram -> scan -> counting-sort into LDS
// staging -> bucket-ordered burst write-out. Each output line is fully written within ~1
// sub-tile by adjacent threads -> L2 merges, single write-back. Everything else unchanged:
//   k_grp  : per-bucket LDS group-by-col -> srt u32 CSR payload + cptr + dinv + g1/acc1
//   k_csr  : 8 lanes/col serial register accumulate; no LDS/barriers/atomics
//   h[c] = b + dinv[c]*( g[c] + sum_e w_e * g[row_e] ),  g = dinv * (prev @ W)

#define SH 6
#define RB 64
#define KMAX 2048           // N <= 131072 (row packs in 17 bits)
#define TPB 256
#define BCAP 8192           // per-bucket LDS capacity in k_grp
#define PT 512              // k_part threads
#define ST 8192             // k_part sub-tile edges

typedef unsigned short ushort_t;
typedef unsigned char u8;

__device__ __forceinline__ ushort_t f2bf(float v) {
    unsigned u = __float_as_uint(v);
    u += 0x7FFFu + ((u >> 16) & 1u);   // RNE
    return (ushort_t)(u >> 16);
}

__device__ __forceinline__ unsigned quantw(float w) {
    unsigned wq = (unsigned)__float2int_rn(w * 32768.0f);
    return wq > 32767u ? 32767u : wq;
}

// ---------- bucket counts ----------
__global__ __launch_bounds__(TPB)
void k_cnt(const int* __restrict__ col, unsigned* __restrict__ bcnt, int E, int K) {
    __shared__ unsigned lh[KMAX];
    for (int i = threadIdx.x; i < K; i += TPB) lh[i] = 0u;
    __syncthreads();
    for (int e = blockIdx.x * TPB + threadIdx.x; e < E; e += gridDim.x * TPB)
        atomicAdd(&lh[col[e] >> SH], 1u);
    __syncthreads();
    for (int i = threadIdx.x; i < K; i += TPB)
        if (lh[i]) atomicAdd(&bcnt[i], lh[i]);
}

// ---------- exclusive scan -> bst, bcur ----------
__global__ void k_scan(const unsigned* __restrict__ cnt, unsigned* __restrict__ start,
                       unsigned* __restrict__ cursor, int K) {
    __shared__ unsigned a[KMAX], b[KMAX];
    int t = threadIdx.x;  // 1024
    for (int i = t; i < KMAX; i += 1024) a[i] = (i < K) ? cnt[i] : 0u;
    __syncthreads();
    unsigned *src = a, *dst = b;
    for (int off = 1; off < KMAX; off <<= 1) {
        for (int i = t; i < KMAX; i += 1024)
            dst[i] = (i >= off) ? src[i] + src[i - off] : src[i];
        __syncthreads();
        unsigned* tmp = src; src = dst; dst = tmp;
    }
    for (int i = t; i < K; i += 1024) {
        unsigned ex = (i == 0) ? 0u : src[i - 1];
        start[i] = ex; cursor[i] = ex;
    }
}

// ---------- LDS-staged partition: bucket-sorted burst writes, no line thrash ----------
__global__ __launch_bounds__(PT)
void k_part(const int* __restrict__ row, const int* __restrict__ col,
            const float* __restrict__ ew, unsigned* __restrict__ bcur,
            unsigned* __restrict__ brp, u8* __restrict__ bcl, int E, int K) {
    __shared__ unsigned A[KMAX], B[KMAX], lcur[KMAX];   // 24KB
    __shared__ unsigned sp[ST], sc[ST];                 // 64KB staging
    int tid = threadIdx.x;
    int tile = (E + gridDim.x - 1) / gridDim.x;
    int e0 = blockIdx.x * tile, e1 = min(e0 + tile, E);
    if (e0 >= e1) return;

    // Phase A: block-tile histogram -> reserve one contiguous chunk per bucket
    for (int i = tid; i < KMAX; i += PT) A[i] = 0u;
    __syncthreads();
    for (int e = e0 + tid; e < e1; e += PT) atomicAdd(&A[col[e] >> SH], 1u);
    __syncthreads();
    for (int i = tid; i < K; i += PT) {
        unsigned c = A[i];
        lcur[i] = c ? atomicAdd(&bcur[i], c) : 0u;
    }
    __syncthreads();

    // Phase B: sub-tiles -> LDS counting-sort -> bucket-ordered write-out
    for (int s0 = e0; s0 < e1; s0 += ST) {
        int cnt = min(ST, e1 - s0);
        for (int i = tid; i < KMAX; i += PT) A[i] = 0u;
        __syncthreads();
        for (int j = tid; j < cnt; j += PT) atomicAdd(&A[col[s0 + j] >> SH], 1u);
        __syncthreads();
        unsigned *src = A, *dst = B;                    // inclusive scan (Hillis-Steele)
        for (int off = 1; off < KMAX; off <<= 1) {
            for (int i = tid; i < KMAX; i += PT)
                dst[i] = (i >= off) ? src[i] + src[i - off] : src[i];
            __syncthreads();
            unsigned* t = src; src = dst; dst = t;
        }
        for (int i = tid; i < KMAX; i += PT)            // dst := exclusive cursor
            dst[i] = i ? src[i - 1] : 0u;
        __syncthreads();
        for (int j = tid; j < cnt; j += PT) {           // counting-sort into staging
            int e = s0 + j;
            int c = col[e];
            unsigned p = atomicAdd(&dst[c >> SH], 1u);
            sp[p] = (unsigned)row[e] | (quantw(ew[e]) << 17);
            sc[p] = (unsigned)c;
        }
        __syncthreads();
        for (int j = tid; j < cnt; j += PT) {           // burst write-out, bucket-ordered
            unsigned c = sc[j], b = c >> SH;
            unsigned excl = b ? src[b - 1] : 0u;
            unsigned d = lcur[b] + ((unsigned)j - excl);
            brp[d] = sp[j];
            bcl[d] = (u8)(c & 63u);
        }
        __syncthreads();
        for (int i = tid; i < KMAX; i += PT)            // advance cursors
            lcur[i] += src[i] - (i ? src[i - 1] : 0u);
        __syncthreads();
    }
}

// ---------- per-bucket: group-by-col -> srt CSR payload + cptr + dinv + g1/acc1 seed ----
__global__ __launch_bounds__(TPB)
void k_grp(const unsigned* __restrict__ brp, const u8* __restrict__ bcl,
           const unsigned* __restrict__ bst, const unsigned* __restrict__ bcnt,
           const float* __restrict__ x, const float* __restrict__ W1,
           unsigned* __restrict__ srt, unsigned* __restrict__ cptr,
           float* __restrict__ dinv, unsigned* __restrict__ g1b,
           float* __restrict__ acc1, int N, int E) {
    int k = blockIdx.x, node0 = k << SH;
    __shared__ unsigned ebuf[BCAP];          // 32KB (reused as gtmp after scatter)
    __shared__ u8 cbuf[BCAP];                // 8KB
    __shared__ unsigned cnt64[RB], st64[RB], dq[RB];
    __shared__ float dl[RB], lx[RB * 3], lw[48];
    int tid = threadIdx.x;
    unsigned s = bst[k], c = bcnt[k];
    if (tid < RB) { cnt64[tid] = 0u; dq[tid] = 0u; }
    if (tid < 48) lw[tid] = W1[tid];
    int nn = min(RB, N - node0);
    for (int i = tid; i < nn * 3; i += TPB) lx[i] = x[(size_t)node0 * 3 + i];
    __syncthreads();

    bool fits = (c <= (unsigned)BCAP);
    if (fits) {
        for (unsigned j = tid; j < c; j += TPB) {
            unsigned p = brp[s + j];
            unsigned cl = bcl[s + j];
            ebuf[j] = p; cbuf[j] = (u8)cl;
            atomicAdd(&cnt64[cl], 1u);
            atomicAdd(&dq[cl], p >> 17);
        }
        __syncthreads();
        if (tid == 0) {                                  // tiny serial scan of 64
            unsigned acc = 0;
            for (int i = 0; i < RB; i++) { st64[i] = acc; acc += cnt64[i]; cnt64[i] = 0u; }
        }
        __syncthreads();
        for (unsigned j = tid; j < c; j += TPB) {
            unsigned cl = cbuf[j];
            unsigned pos = st64[cl] + atomicAdd(&cnt64[cl], 1u);
            srt[s + pos] = ebuf[j];                      // within-bucket 8KB range
        }
    } else {                                             // 2-pass fallback (rare)
        for (unsigned j = tid; j < c; j += TPB) {
            unsigned cl = bcl[s + j];
            atomicAdd(&cnt64[cl], 1u);
            atomicAdd(&dq[cl], brp[s + j] >> 17);
        }
        __syncthreads();
        if (tid == 0) {
            unsigned acc = 0;
            for (int i = 0; i < RB; i++) { st64[i] = acc; acc += cnt64[i]; cnt64[i] = 0u; }
        }
        __syncthreads();
        for (unsigned j = tid; j < c; j += TPB) {
            unsigned cl = bcl[s + j];
            unsigned pos = st64[cl] + atomicAdd(&cnt64[cl], 1u);
            srt[s + pos] = brp[s + j];
        }
    }
    __syncthreads();
    if (tid < RB) {
        float d = rsqrtf(1.0f + (float)dq[tid] * (1.0f / 32768.0f));  // self-loop +1
        dl[tid] = d;
        if (tid < nn) {
            dinv[node0 + tid] = d;
            cptr[node0 + tid] = s + st64[tid];
        }
    }
    if (tid == 0 && node0 + nn == N) cptr[N] = (unsigned)E;  // sentinel
    __syncthreads();
    float* gtmp = (float*)ebuf;   // safe: all ebuf reads complete
    for (int idx = tid; idx < nn * 16; idx += TPB) {
        int n = idx >> 4, f = idx & 15;
        float v = dl[n] * (lx[n * 3] * lw[f] + lx[n * 3 + 1] * lw[16 + f] +
                           lx[n * 3 + 2] * lw[32 + f]);
        acc1[(size_t)(node0 + n) * 16 + f] = v;
        gtmp[idx] = v;
    }
    __syncthreads();
    for (int idx = tid; idx < nn * 8; idx += TPB) {
        int n = idx >> 3, q = idx & 7;
        g1b[(size_t)(node0 + n) * 8 + q] =
            (unsigned)f2bf(gtmp[n * 16 + 2 * q]) |
            ((unsigned)f2bf(gtmp[n * 16 + 2 * q + 1]) << 16);
    }
}

// ---------- consumer: 8 lanes/col, serial register accumulate, no barriers ----------
__global__ __launch_bounds__(TPB)
void k_csr(const unsigned* __restrict__ srt, const unsigned* __restrict__ cptr,
           const unsigned* __restrict__ gb, float* __restrict__ acc, int N) {
    int t = blockIdx.x * TPB + threadIdx.x;
    int c = t >> 3, f2 = t & 7;
    if (c >= N) return;
    unsigned e = cptr[c], end = cptr[c + 1];
    float a = 0.0f, b = 0.0f;
#pragma unroll 4
    for (; e < end; ++e) {
        unsigned m = srt[e];                         // same addr across 8 lanes -> merged
        float w = (float)(m >> 17) * (1.0f / 32768.0f);
        unsigned u = gb[(size_t)(m & 0x1FFFFu) * 8 + f2];  // bf16x2, L2-resident table
        a = fmaf(w, __uint_as_float(u << 16), a);
        b = fmaf(w, __uint_as_float(u & 0xFFFF0000u), b);
    }
    float2* p = (float2*)&acc[(size_t)c * 16 + 2 * f2];
    float2 v = *p;                                   // exclusive owner: plain RMW
    v.x += a; v.y += b;
    *p = v;
}

// ---------- mid: h1 = relu(b1 + dinv*acc1); g2 = dinv*(h1@W2) -> bf16 + acc2 seed ----------
__global__ void k_mid(const float* __restrict__ acc1, const float* __restrict__ dinv,
                      const float* __restrict__ b1, const float* __restrict__ W2,
                      unsigned* __restrict__ g2b, float* __restrict__ acc2, int N) {
    __shared__ float t[16][16];
    __shared__ float go[16][16];
    __shared__ float w2[256];
    int tid = threadIdx.x;
    int il = tid >> 4, f = tid & 15;
    int i = blockIdx.x * 16 + il;
    w2[tid] = W2[tid];
    float v = 0.0f, d = 0.0f;
    if (i < N) {
        d = dinv[i];
        v = b1[f] + d * acc1[(size_t)i * 16 + f];
        v = v > 0.0f ? v : 0.0f;
    }
    t[il][f] = v;
    __syncthreads();
    float r = 0.0f;
    if (i < N) {
        float o = 0.0f;
#pragma unroll
        for (int kk = 0; kk < 16; kk++) o += t[il][kk] * w2[kk * 16 + f];
        r = d * o;
        acc2[(size_t)i * 16 + f] = r;
    }
    go[il][f] = r;
    __syncthreads();
    if (tid < 128) {
        int il2 = tid >> 3, q = tid & 7;
        int i2 = blockIdx.x * 16 + il2;
        if (i2 < N)
            g2b[(size_t)i2 * 8 + q] = (unsigned)f2bf(go[il2][2 * q]) |
                                      ((unsigned)f2bf(go[il2][2 * q + 1]) << 16);
    }
}

// ---------- pool: h2 = relu(b2 + dinv*acc2) folded into sorted-batch pool ----------
#define PC 1024
__global__ void k_pool(const float* __restrict__ acc2, const float* __restrict__ dinv,
                       const float* __restrict__ b2, const int* __restrict__ batch,
                       float* __restrict__ pooled, int N, int G) {
    int b0 = blockIdx.x * PC;
    int nodes = min(PC, N - b0);
    __shared__ float lacc[64 * 16];
    __shared__ int lbat[PC];
    int tid = threadIdx.x;  // 256
    for (int i = tid; i < nodes; i += 256) lbat[i] = batch[b0 + i];
    __syncthreads();
    int gmin = lbat[0], gmax = lbat[nodes - 1];
    bool fits = (gmax - gmin < 64);
    if (fits) {
        for (int i = tid; i < 64 * 16; i += 256) lacc[i] = 0.0f;
        __syncthreads();
    }
    for (int idx = tid; idx < nodes * 16; idx += 256) {
        int i = idx >> 4, f = idx & 15;
        int n = b0 + i;
        float d = dinv[n];
        float v = b2[f] + d * acc2[(size_t)n * 16 + f];
        v = v > 0.0f ? v : 0.0f;
        if (fits) atomicAdd(&lacc[(lbat[i] - gmin) * 16 + f], v);
        else      atomicAdd(&pooled[lbat[i] * 16 + f], v);
    }
    if (fits) {
        __syncthreads();
        for (int idx = tid; idx < 64 * 16; idx += 256) {
            int g = gmin + (idx >> 4);
            float v = lacc[idx];
            if (g < G && v != 0.0f) atomicAdd(&pooled[g * 16 + (idx & 15)], v);
        }
    }
}

__global__ void k_final(const float* __restrict__ pooled, const float* __restrict__ Wlin,
                        const float* __restrict__ blin, float* __restrict__ out, int G) {
    int t = blockIdx.x * blockDim.x + threadIdx.x;
    int g = t / 7, j = t % 7;
    if (g >= G) return;
    float v = blin[j];
#pragma unroll
    for (int f = 0; f < 16; f++) v += pooled[g * 16 + f] * Wlin[f * 7 + j];
    out[g * 7 + j] = v;
}

static inline int cdiv_i(long long a, long long b) { return (int)((a + b - 1) / b); }

extern "C" void kernel_launch(void* const* d_in, const int* in_sizes, int n_in,
                              void* d_out, int out_size, void* d_ws, size_t ws_size,
                              hipStream_t stream) {
    const float* x     = (const float*)d_in[0];
    const int*   ei    = (const int*)d_in[1];
    const float* ew    = (const float*)d_in[2];
    const int*   batch = (const int*)d_in[3];
    const float* W1    = (const float*)d_in[4];
    const float* b1    = (const float*)d_in[5];
    const float* W2    = (const float*)d_in[6];
    const float* b2    = (const float*)d_in[7];
    const float* Wlin  = (const float*)d_in[8];
    const float* blin  = (const float*)d_in[9];
    float* out = (float*)d_out;

    const int N = in_sizes[0] / 3;
    const int E = in_sizes[2];
    const int G = out_size / 7;
    const int K = (N + RB - 1) >> SH;   // 1563
    const int* row = ei;
    const int* col = ei + E;

    // layout: brp | bcl | [zero: bcnt, bcur, pooled] | bst | srt | cptr | dinv | g1b | g2b | acc1 | acc2
    unsigned* brp    = (unsigned*)d_ws;                     // E
    u8*       bcl    = (u8*)(brp + E);                      // E (E%4==0)
    unsigned* bcnt   = (unsigned*)(bcl + E);                // KMAX
    unsigned* bcur   = bcnt + KMAX;                         // KMAX
    float*    pooled = (float*)(bcur + KMAX);               // G*16
    unsigned* bst    = (unsigned*)(pooled + (size_t)G*16);  // KMAX
    unsigned* srt    = bst + KMAX;                          // E
    unsigned* cptr   = srt + E;                             // N+1
    float*    dinv   = (float*)(cptr + N + 1);              // N
    unsigned* g1b    = (unsigned*)(dinv + N);               // N*8 (bf16 x16)
    unsigned* g2b    = g1b + (size_t)N * 8;                 // N*8
    float*    acc1   = (float*)(g2b + (size_t)N * 8);       // N*16
    float*    acc2   = acc1 + (size_t)N * 16;               // N*16

    hipMemsetAsync(bcnt, 0, (2 * KMAX + (size_t)G * 16) * sizeof(unsigned), stream);

    // CSR build: bucket counts -> scan -> LDS-staged partition -> per-bucket group-by-col
    k_cnt<<<256, TPB, 0, stream>>>(col, bcnt, E, K);
    k_scan<<<1, 1024, 0, stream>>>(bcnt, bst, bcur, K);
    k_part<<<128, PT, 0, stream>>>(row, col, ew, bcur, brp, bcl, E, K);
    k_grp<<<K, TPB, 0, stream>>>(brp, bcl, bst, bcnt, x, W1, srt, cptr, dinv, g1b, acc1, N, E);

    // layer 1: barrier-free CSR gather/reduce
    k_csr<<<cdiv_i((long long)N * 8, TPB), TPB, 0, stream>>>(srt, cptr, g1b, acc1, N);

    // mid: h1 -> g2(bf16) + acc2 seed
    k_mid<<<cdiv_i(N, 16), TPB, 0, stream>>>(acc1, dinv, b1, W2, g2b, acc2, N);

    // layer 2
    k_csr<<<cdiv_i((long long)N * 8, TPB), TPB, 0, stream>>>(srt, cptr, g2b, acc2, N);

    // pool + head
    k_pool<<<cdiv_i(N, PC), TPB, 0, stream>>>(acc2, dinv, b2, batch, pooled, N, G);
    k_final<<<cdiv_i((long long)G * 7, TPB), TPB, 0, stream>>>(pooled, Wlin, blin, out, G);
}

// Round 4
// 292.541 us; speedup vs baseline: 1.1380x; 1.1380x over previous
//
#include <hip/hip_runtime.h>

// GCN 2-layer + pool + head, R19: latency-restructured partition pass.
// R18's k_part (120us) was latency-bound (VALU 4%, HBM 8%, occ 10%): grid 128 -> half the
// CUs idle; 11-round Hillis-Steele scan + ~17 barriers per sub-tile with 8 waves/block.
// Fix: (a) k_cnt tile-aligned + stores per-block hist bh -> k_part Phase A reads 6KB row
// instead of re-histogramming its col tile; (b) grid 256 (all CUs), ST 4096, LDS 64KB;
// (c) two-level scan (4-serial + __shfl_up wave scan + 8 wave-totals) = 3 barriers, ~8
// barriers/sub-tile total. Payload + all downstream kernels unchanged (numerics identical).
//   k_grp  : per-bucket LDS group-by-col -> srt u32 CSR payload + cptr + dinv + g1/acc1
//   k_csr  : 8 lanes/col serial register accumulate; no LDS/barriers/atomics
//   h[c] = b + dinv[c]*( g[c] + sum_e w_e * g[row_e] ),  g = dinv * (prev @ W)

#define SH 6
#define RB 64
#define KMAX 2048           // N <= 131072 (row packs in 17 bits)
#define TPB 256
#define BCAP 8192           // per-bucket LDS capacity in k_grp
#define PT 512              // k_part threads
#define ST 4096             // k_part sub-tile edges
#define PB 256              // partition grid (must match k_cnt grid)

typedef unsigned short ushort_t;
typedef unsigned char u8;

__device__ __forceinline__ ushort_t f2bf(float v) {
    unsigned u = __float_as_uint(v);
    u += 0x7FFFu + ((u >> 16) & 1u);   // RNE
    return (ushort_t)(u >> 16);
}

__device__ __forceinline__ unsigned quantw(float w) {
    unsigned wq = (unsigned)__float2int_rn(w * 32768.0f);
    return wq > 32767u ? 32767u : wq;
}

// ---------- bucket counts, tile-aligned; stores per-block hist for k_part ----------
__global__ __launch_bounds__(TPB)
void k_cnt(const int* __restrict__ col, unsigned* __restrict__ bcnt,
           unsigned* __restrict__ bh, int E, int K) {
    __shared__ unsigned lh[KMAX];
    int tile = (E + gridDim.x - 1) / gridDim.x;
    int e0 = blockIdx.x * tile, e1 = min(e0 + tile, E);
    for (int i = threadIdx.x; i < K; i += TPB) lh[i] = 0u;
    __syncthreads();
    for (int e = e0 + threadIdx.x; e < e1; e += TPB)
        atomicAdd(&lh[col[e] >> SH], 1u);
    __syncthreads();
    for (int i = threadIdx.x; i < K; i += TPB) {
        unsigned c = lh[i];
        bh[(size_t)blockIdx.x * KMAX + i] = c;
        if (c) atomicAdd(&bcnt[i], c);
    }
}

// ---------- exclusive scan -> bst, bcur ----------
__global__ void k_scan(const unsigned* __restrict__ cnt, unsigned* __restrict__ start,
                       unsigned* __restrict__ cursor, int K) {
    __shared__ unsigned a[KMAX], b[KMAX];
    int t = threadIdx.x;  // 1024
    for (int i = t; i < KMAX; i += 1024) a[i] = (i < K) ? cnt[i] : 0u;
    __syncthreads();
    unsigned *src = a, *dst = b;
    for (int off = 1; off < KMAX; off <<= 1) {
        for (int i = t; i < KMAX; i += 1024)
            dst[i] = (i >= off) ? src[i] + src[i - off] : src[i];
        __syncthreads();
        unsigned* tmp = src; src = dst; dst = tmp;
    }
    for (int i = t; i < K; i += 1024) {
        unsigned ex = (i == 0) ? 0u : src[i - 1];
        start[i] = ex; cursor[i] = ex;
    }
}

// ---------- LDS-staged partition: bucket-sorted burst writes ----------
__global__ __launch_bounds__(PT)
void k_part(const int* __restrict__ row, const int* __restrict__ col,
            const float* __restrict__ ew, const unsigned* __restrict__ bh,
            unsigned* __restrict__ bcur, unsigned* __restrict__ brp,
            u8* __restrict__ bcl, int E, int K) {
    __shared__ unsigned A[KMAX];                 // sub-tile counts (8KB)
    __shared__ unsigned X[KMAX];                 // sub-tile exclusive scan (8KB)
    __shared__ unsigned cur[KMAX];               // scatter cursors (8KB)
    __shared__ unsigned lcur[KMAX];              // global chunk cursors (8KB)
    __shared__ unsigned sp[ST], sc[ST];          // staging (32KB)
    __shared__ unsigned wsum[PT / 64];
    int tid = threadIdx.x;
    int tile = (E + gridDim.x - 1) / gridDim.x;
    int e0 = blockIdx.x * tile, e1 = min(e0 + tile, E);
    if (e0 >= e1) return;

    // Phase A: reserve one contiguous chunk per bucket from precomputed hist row
    for (int i = tid; i < K; i += PT) {
        unsigned c = bh[(size_t)blockIdx.x * KMAX + i];
        lcur[i] = c ? atomicAdd(&bcur[i], c) : 0u;
    }

    // Phase B: sub-tiles -> LDS counting-sort -> bucket-ordered write-out
    for (int s0 = e0; s0 < e1; s0 += ST) {
        int cnt = min(ST, e1 - s0);
        for (int i = tid; i < KMAX; i += PT) A[i] = 0u;
        __syncthreads();
        for (int j = tid; j < cnt; j += PT) atomicAdd(&A[col[s0 + j] >> SH], 1u);
        __syncthreads();
        // two-level exclusive scan of A[0..KMAX): 4-serial + wave shfl + wave totals
        {
            int t4 = tid << 2;
            unsigned a0 = A[t4], a1 = A[t4 + 1], a2 = A[t4 + 2], a3 = A[t4 + 3];
            unsigned ts = a0 + a1 + a2 + a3;
            unsigned v = ts;
#pragma unroll
            for (int o = 1; o < 64; o <<= 1) {
                unsigned u = __shfl_up(v, o, 64);
                if ((tid & 63) >= o) v += u;
            }
            if ((tid & 63) == 63) wsum[tid >> 6] = v;
            __syncthreads();
            if (tid == 0) {
                unsigned acc = 0;
#pragma unroll
                for (int w = 0; w < PT / 64; w++) { unsigned x = wsum[w]; wsum[w] = acc; acc += x; }
            }
            __syncthreads();
            unsigned ex = wsum[tid >> 6] + (v - ts);
            X[t4] = ex;                cur[t4] = ex;
            X[t4 + 1] = ex + a0;       cur[t4 + 1] = ex + a0;
            X[t4 + 2] = ex + a0 + a1;  cur[t4 + 2] = ex + a0 + a1;
            X[t4 + 3] = ex + a0 + a1 + a2; cur[t4 + 3] = ex + a0 + a1 + a2;
        }
        __syncthreads();
        for (int j = tid; j < cnt; j += PT) {        // counting-sort into staging
            int e = s0 + j;
            int c = col[e];
            unsigned p = atomicAdd(&cur[c >> SH], 1u);
            sp[p] = (unsigned)row[e] | (quantw(ew[e]) << 17);
            sc[p] = (unsigned)c;
        }
        __syncthreads();
        for (int j = tid; j < cnt; j += PT) {        // burst write-out, bucket-ordered
            unsigned c = sc[j], b = c >> SH;
            unsigned d = lcur[b] + ((unsigned)j - X[b]);
            brp[d] = sp[j];
            bcl[d] = (u8)(c & 63u);
        }
        __syncthreads();
        for (int i = tid; i < KMAX; i += PT)         // advance chunk cursors
            lcur[i] += A[i];
        __syncthreads();
    }
}

// ---------- per-bucket: group-by-col -> srt CSR payload + cptr + dinv + g1/acc1 seed ----
__global__ __launch_bounds__(TPB)
void k_grp(const unsigned* __restrict__ brp, const u8* __restrict__ bcl,
           const unsigned* __restrict__ bst, const unsigned* __restrict__ bcnt,
           const float* __restrict__ x, const float* __restrict__ W1,
           unsigned* __restrict__ srt, unsigned* __restrict__ cptr,
           float* __restrict__ dinv, unsigned* __restrict__ g1b,
           float* __restrict__ acc1, int N, int E) {
    int k = blockIdx.x, node0 = k << SH;
    __shared__ unsigned ebuf[BCAP];          // 32KB (reused as gtmp after scatter)
    __shared__ u8 cbuf[BCAP];                // 8KB
    __shared__ unsigned cnt64[RB], st64[RB], dq[RB];
    __shared__ float dl[RB], lx[RB * 3], lw[48];
    int tid = threadIdx.x;
    unsigned s = bst[k], c = bcnt[k];
    if (tid < RB) { cnt64[tid] = 0u; dq[tid] = 0u; }
    if (tid < 48) lw[tid] = W1[tid];
    int nn = min(RB, N - node0);
    for (int i = tid; i < nn * 3; i += TPB) lx[i] = x[(size_t)node0 * 3 + i];
    __syncthreads();

    bool fits = (c <= (unsigned)BCAP);
    if (fits) {
        for (unsigned j = tid; j < c; j += TPB) {
            unsigned p = brp[s + j];
            unsigned cl = bcl[s + j];
            ebuf[j] = p; cbuf[j] = (u8)cl;
            atomicAdd(&cnt64[cl], 1u);
            atomicAdd(&dq[cl], p >> 17);
        }
        __syncthreads();
        if (tid == 0) {                                  // tiny serial scan of 64
            unsigned acc = 0;
            for (int i = 0; i < RB; i++) { st64[i] = acc; acc += cnt64[i]; cnt64[i] = 0u; }
        }
        __syncthreads();
        for (unsigned j = tid; j < c; j += TPB) {
            unsigned cl = cbuf[j];
            unsigned pos = st64[cl] + atomicAdd(&cnt64[cl], 1u);
            srt[s + pos] = ebuf[j];                      // within-bucket 8KB range
        }
    } else {                                             // 2-pass fallback (rare)
        for (unsigned j = tid; j < c; j += TPB) {
            unsigned cl = bcl[s + j];
            atomicAdd(&cnt64[cl], 1u);
            atomicAdd(&dq[cl], brp[s + j] >> 17);
        }
        __syncthreads();
        if (tid == 0) {
            unsigned acc = 0;
            for (int i = 0; i < RB; i++) { st64[i] = acc; acc += cnt64[i]; cnt64[i] = 0u; }
        }
        __syncthreads();
        for (unsigned j = tid; j < c; j += TPB) {
            unsigned cl = bcl[s + j];
            unsigned pos = st64[cl] + atomicAdd(&cnt64[cl], 1u);
            srt[s + pos] = brp[s + j];
        }
    }
    __syncthreads();
    if (tid < RB) {
        float d = rsqrtf(1.0f + (float)dq[tid] * (1.0f / 32768.0f));  // self-loop +1
        dl[tid] = d;
        if (tid < nn) {
            dinv[node0 + tid] = d;
            cptr[node0 + tid] = s + st64[tid];
        }
    }
    if (tid == 0 && node0 + nn == N) cptr[N] = (unsigned)E;  // sentinel
    __syncthreads();
    float* gtmp = (float*)ebuf;   // safe: all ebuf reads complete
    for (int idx = tid; idx < nn * 16; idx += TPB) {
        int n = idx >> 4, f = idx & 15;
        float v = dl[n] * (lx[n * 3] * lw[f] + lx[n * 3 + 1] * lw[16 + f] +
                           lx[n * 3 + 2] * lw[32 + f]);
        acc1[(size_t)(node0 + n) * 16 + f] = v;
        gtmp[idx] = v;
    }
    __syncthreads();
    for (int idx = tid; idx < nn * 8; idx += TPB) {
        int n = idx >> 3, q = idx & 7;
        g1b[(size_t)(node0 + n) * 8 + q] =
            (unsigned)f2bf(gtmp[n * 16 + 2 * q]) |
            ((unsigned)f2bf(gtmp[n * 16 + 2 * q + 1]) << 16);
    }
}

// ---------- consumer: 8 lanes/col, serial register accumulate, no barriers ----------
__global__ __launch_bounds__(TPB)
void k_csr(const unsigned* __restrict__ srt, const unsigned* __restrict__ cptr,
           const unsigned* __restrict__ gb, float* __restrict__ acc, int N) {
    int t = blockIdx.x * TPB + threadIdx.x;
    int c = t >> 3, f2 = t & 7;
    if (c >= N) return;
    unsigned e = cptr[c], end = cptr[c + 1];
    float a = 0.0f, b = 0.0f;
#pragma unroll 4
    for (; e < end; ++e) {
        unsigned m = srt[e];                         // same addr across 8 lanes -> merged
        float w = (float)(m >> 17) * (1.0f / 32768.0f);
        unsigned u = gb[(size_t)(m & 0x1FFFFu) * 8 + f2];  // bf16x2, L2-resident table
        a = fmaf(w, __uint_as_float(u << 16), a);
        b = fmaf(w, __uint_as_float(u & 0xFFFF0000u), b);
    }
    float2* p = (float2*)&acc[(size_t)c * 16 + 2 * f2];
    float2 v = *p;                                   // exclusive owner: plain RMW
    v.x += a; v.y += b;
    *p = v;
}

// ---------- mid: h1 = relu(b1 + dinv*acc1); g2 = dinv*(h1@W2) -> bf16 + acc2 seed ----------
__global__ void k_mid(const float* __restrict__ acc1, const float* __restrict__ dinv,
                      const float* __restrict__ b1, const float* __restrict__ W2,
                      unsigned* __restrict__ g2b, float* __restrict__ acc2, int N) {
    __shared__ float t[16][16];
    __shared__ float go[16][16];
    __shared__ float w2[256];
    int tid = threadIdx.x;
    int il = tid >> 4, f = tid & 15;
    int i = blockIdx.x * 16 + il;
    w2[tid] = W2[tid];
    float v = 0.0f, d = 0.0f;
    if (i < N) {
        d = dinv[i];
        v = b1[f] + d * acc1[(size_t)i * 16 + f];
        v = v > 0.0f ? v : 0.0f;
    }
    t[il][f] = v;
    __syncthreads();
    float r = 0.0f;
    if (i < N) {
        float o = 0.0f;
#pragma unroll
        for (int kk = 0; kk < 16; kk++) o += t[il][kk] * w2[kk * 16 + f];
        r = d * o;
        acc2[(size_t)i * 16 + f] = r;
    }
    go[il][f] = r;
    __syncthreads();
    if (tid < 128) {
        int il2 = tid >> 3, q = tid & 7;
        int i2 = blockIdx.x * 16 + il2;
        if (i2 < N)
            g2b[(size_t)i2 * 8 + q] = (unsigned)f2bf(go[il2][2 * q]) |
                                      ((unsigned)f2bf(go[il2][2 * q + 1]) << 16);
    }
}

// ---------- pool: h2 = relu(b2 + dinv*acc2) folded into sorted-batch pool ----------
#define PC 1024
__global__ void k_pool(const float* __restrict__ acc2, const float* __restrict__ dinv,
                       const float* __restrict__ b2, const int* __restrict__ batch,
                       float* __restrict__ pooled, int N, int G) {
    int b0 = blockIdx.x * PC;
    int nodes = min(PC, N - b0);
    __shared__ float lacc[64 * 16];
    __shared__ int lbat[PC];
    int tid = threadIdx.x;  // 256
    for (int i = tid; i < nodes; i += 256) lbat[i] = batch[b0 + i];
    __syncthreads();
    int gmin = lbat[0], gmax = lbat[nodes - 1];
    bool fits = (gmax - gmin < 64);
    if (fits) {
        for (int i = tid; i < 64 * 16; i += 256) lacc[i] = 0.0f;
        __syncthreads();
    }
    for (int idx = tid; idx < nodes * 16; idx += 256) {
        int i = idx >> 4, f = idx & 15;
        int n = b0 + i;
        float d = dinv[n];
        float v = b2[f] + d * acc2[(size_t)n * 16 + f];
        v = v > 0.0f ? v : 0.0f;
        if (fits) atomicAdd(&lacc[(lbat[i] - gmin) * 16 + f], v);
        else      atomicAdd(&pooled[lbat[i] * 16 + f], v);
    }
    if (fits) {
        __syncthreads();
        for (int idx = tid; idx < 64 * 16; idx += 256) {
            int g = gmin + (idx >> 4);
            float v = lacc[idx];
            if (g < G && v != 0.0f) atomicAdd(&pooled[g * 16 + (idx & 15)], v);
        }
    }
}

__global__ void k_final(const float* __restrict__ pooled, const float* __restrict__ Wlin,
                        const float* __restrict__ blin, float* __restrict__ out, int G) {
    int t = blockIdx.x * blockDim.x + threadIdx.x;
    int g = t / 7, j = t % 7;
    if (g >= G) return;
    float v = blin[j];
#pragma unroll
    for (int f = 0; f < 16; f++) v += pooled[g * 16 + f] * Wlin[f * 7 + j];
    out[g * 7 + j] = v;
}

static inline int cdiv_i(long long a, long long b) { return (int)((a + b - 1) / b); }

extern "C" void kernel_launch(void* const* d_in, const int* in_sizes, int n_in,
                              void* d_out, int out_size, void* d_ws, size_t ws_size,
                              hipStream_t stream) {
    const float* x     = (const float*)d_in[0];
    const int*   ei    = (const int*)d_in[1];
    const float* ew    = (const float*)d_in[2];
    const int*   batch = (const int*)d_in[3];
    const float* W1    = (const float*)d_in[4];
    const float* b1    = (const float*)d_in[5];
    const float* W2    = (const float*)d_in[6];
    const float* b2    = (const float*)d_in[7];
    const float* Wlin  = (const float*)d_in[8];
    const float* blin  = (const float*)d_in[9];
    float* out = (float*)d_out;

    const int N = in_sizes[0] / 3;
    const int E = in_sizes[2];
    const int G = out_size / 7;
    const int K = (N + RB - 1) >> SH;   // 1563
    const int* row = ei;
    const int* col = ei + E;

    // layout: brp | bcl | [zero: bcnt, bcur, pooled] | bst | bh | srt | cptr | dinv | g1b | g2b | acc1 | acc2
    unsigned* brp    = (unsigned*)d_ws;                     // E
    u8*       bcl    = (u8*)(brp + E);                      // E (E%4==0)
    unsigned* bcnt   = (unsigned*)(bcl + E);                // KMAX
    unsigned* bcur   = bcnt + KMAX;                         // KMAX
    float*    pooled = (float*)(bcur + KMAX);               // G*16
    unsigned* bst    = (unsigned*)(pooled + (size_t)G*16);  // KMAX
    unsigned* bh     = bst + KMAX;                          // PB*KMAX (2MB)
    unsigned* srt    = bh + (size_t)PB * KMAX;              // E
    unsigned* cptr   = srt + E;                             // N+1
    float*    dinv   = (float*)(cptr + N + 1);              // N
    unsigned* g1b    = (unsigned*)(dinv + N);               // N*8 (bf16 x16)
    unsigned* g2b    = g1b + (size_t)N * 8;                 // N*8
    float*    acc1   = (float*)(g2b + (size_t)N * 8);       // N*16
    float*    acc2   = acc1 + (size_t)N * 16;               // N*16

    hipMemsetAsync(bcnt, 0, (2 * KMAX + (size_t)G * 16) * sizeof(unsigned), stream);

    // CSR build: tiled bucket counts(+bh) -> scan -> LDS-staged partition -> group-by-col
    k_cnt<<<PB, TPB, 0, stream>>>(col, bcnt, bh, E, K);
    k_scan<<<1, 1024, 0, stream>>>(bcnt, bst, bcur, K);
    k_part<<<PB, PT, 0, stream>>>(row, col, ew, bh, bcur, brp, bcl, E, K);
    k_grp<<<K, TPB, 0, stream>>>(brp, bcl, bst, bcnt, x, W1, srt, cptr, dinv, g1b, acc1, N, E);

    // layer 1: barrier-free CSR gather/reduce
    k_csr<<<cdiv_i((long long)N * 8, TPB), TPB, 0, stream>>>(srt, cptr, g1b, acc1, N);

    // mid: h1 -> g2(bf16) + acc2 seed
    k_mid<<<cdiv_i(N, 16), TPB, 0, stream>>>(acc1, dinv, b1, W2, g2b, acc2, N);

    // layer 2
    k_csr<<<cdiv_i((long long)N * 8, TPB), TPB, 0, stream>>>(srt, cptr, g2b, acc2, N);

    // pool + head
    k_pool<<<cdiv_i(N, PC), TPB, 0, stream>>>(acc2, dinv, b2, batch, pooled, N, G);
    k_final<<<cdiv_i((long long)G * 7, TPB), TPB, 0, stream>>>(pooled, Wlin, blin, out, G);
}